// Round 2
// baseline (973.913 us; speedup 1.0000x reference)
//
#include <hip/hip_runtime.h>
#include <hip/hip_bf16.h>
#include <stdint.h>

#define NPTS 500000
#define HSIZE (1u << 20)
#define HMASK (HSIZE - 1)
#define FP 72  // sH row pitch in ushorts: 144B rows -> 16B-aligned b128 reads, 2-way-free banks

typedef __attribute__((ext_vector_type(8))) short short8;
typedef __attribute__((ext_vector_type(4))) float float4v;

__device__ __forceinline__ unsigned short f2b(float f) {
    __hip_bfloat16 h = __float2bfloat16(f);
    return __builtin_bit_cast(unsigned short, h);
}
__device__ __forceinline__ float b2f(unsigned short u) {
    return __builtin_bit_cast(float, ((unsigned)u) << 16);
}

// ---- convert W1, W2 (f32, [s][c][j]) to bf16 transposed [s][j][c]; zero gctr ----
__global__ __launch_bounds__(256) void wconv(const float* __restrict__ W1,
                                             const float* __restrict__ W2,
                                             unsigned short* __restrict__ W1T,
                                             unsigned short* __restrict__ W2T,
                                             int* __restrict__ gctr) {
    int i = blockIdx.x * 256 + threadIdx.x;
    if (i < 192) gctr[i] = 0;
    if (i >= 3 * 4096) return;
    int s = i >> 12, rem = i & 4095, c = rem >> 6, j = rem & 63;
    W1T[s * 4096 + j * 64 + c] = f2b(W1[i]);
    W2T[s * 4096 + j * 64 + c] = f2b(W2[i]);
}

// ---- all 3 scales: 64-bit (key,gid) hash insert + per-slot chain + compact slot list ----
__global__ __launch_bounds__(256) void insert3(const int* __restrict__ coords,
                                               unsigned long long* __restrict__ hKV,
                                               int* __restrict__ head,
                                               int* __restrict__ next,
                                               int* __restrict__ cslot,
                                               int* __restrict__ gctr) {
    const int BPS = (NPTS + 255) / 256;  // 1954
    int s = blockIdx.x / BPS;
    int i = (blockIdx.x % BPS) * 256 + threadIdx.x;
    int shift = s + 1;
    unsigned long long* hs = hKV + (size_t)s * HSIZE;
    int* heads = head + (size_t)s * HSIZE;
    int* nexts = next + (size_t)s * NPTS;
    bool active = i < NPTS;
    unsigned h = 0;
    bool inserted = false;
    if (active) {
        int4 cd = ((const int4*)coords)[i];
        int key = (((cd.w * 512 + (cd.x >> shift)) * 512 + (cd.y >> shift)) * 512 +
                   (cd.z >> shift));
        unsigned long long want = (unsigned long long)(unsigned)key | 0xFFFFFFFF00000000ull;
        h = ((unsigned)key * 2654435761u) >> 12;  // top 20 bits
        while (true) {
            unsigned long long prev = atomicCAS(&hs[h], ~0ull, want);
            if (prev == ~0ull) { inserted = true; break; }
            if ((int)(prev & 0xFFFFFFFFull) == key) break;
            h = (h + 1) & HMASK;
        }
        nexts[i] = atomicExch(&heads[h], i);
    }
    unsigned long long mask = __ballot(inserted);
    if (mask) {
        int lane = threadIdx.x & 63;
        int leader = __ffsll((unsigned long long)mask) - 1;
        int base = 0;
        if (lane == leader) base = atomicAdd(&gctr[s * 64], __popcll(mask));
        base = __shfl(base, leader);
        if (inserted) {
            int gid = base + __popcll(mask & ((1ull << lane) - 1ull));
            ((int*)&hs[h])[1] = gid;  // high word; slot can never be CAS'd again
            cslot[(size_t)s * NPTS + gid] = (int)h;
        }
    }
}

// ---- resolve chain heads into a dense gid-indexed array (removes 2 dependent
// random loads from reduce3's critical path; 1.5M independent threads hide latency)
__global__ __launch_bounds__(256) void headfix3(const int* __restrict__ cslot,
                                                const int* __restrict__ head,
                                                const int* __restrict__ gctr,
                                                int* __restrict__ chead) {
    int t = blockIdx.x * 256 + threadIdx.x;
    int s = t / NPTS;
    if (s >= 3) return;
    int gid = t - s * NPTS;
    if (gid >= gctr[s * 64]) return;
    chead[(size_t)s * NPTS + gid] =
        head[(size_t)s * HSIZE + cslot[(size_t)s * NPTS + gid]];
}

// ---- all 3 scales: 16 lanes per group (4 chains in flight per wave), float4/lane,
// walk chain, exact mean -> bf16 vmean[gid] ----
__global__ __launch_bounds__(256) void reduce3(const float4* __restrict__ feats4,
                                               const int* __restrict__ chead,
                                               const int* __restrict__ next,
                                               const int* __restrict__ gctr,
                                               ushort4* __restrict__ vmean4) {
    int t = blockIdx.x * 256 + threadIdx.x;
    int sub = t >> 4;   // group index over 3*NPTS
    int sl = t & 15;    // sublane: 16 x float4 = 64 channels
    int s = sub / NPTS;
    if (s >= 3) return;
    int gid = sub - s * NPTS;
    if (gid >= gctr[s * 64]) return;
    int i = chead[(size_t)s * NPTS + gid];  // dense coalesced load
    const int* nexts = next + (size_t)s * NPTS;
    float4 sum = {0.f, 0.f, 0.f, 0.f};
    int cnt = 0;
    while (i >= 0) {
        float4 v = feats4[(size_t)i * 16 + sl];  // 256B coalesced row
        int ni = nexts[i];                       // independent of v
        sum.x += v.x; sum.y += v.y; sum.z += v.z; sum.w += v.w;
        cnt++;
        i = ni;
    }
    float cf = (float)cnt;
    ushort4 o;
    o.x = f2b(sum.x / cf);
    o.y = f2b(sum.y / cf);
    o.z = f2b(sum.z / cf);
    o.w = f2b(sum.w / cf);
    vmean4[((size_t)s * NPTS + gid) * 16 + sl] = o;
}

// ---- all 3 scales: 8 corners (8 pts/wave), exact first-max argmax, write winning gid ----
__global__ __launch_bounds__(256) void argmax3(const int* __restrict__ coords,
                                               const int2* __restrict__ hKV,
                                               int* __restrict__ idx) {
    const int PPB = 32;                 // points per block (256 thr / 8 corners)
    const int BPS = NPTS / PPB;         // 15625 exactly
    int s = blockIdx.x / BPS;
    int p = (blockIdx.x % BPS) * PPB + (threadIdx.x >> 3);
    int corner = threadIdx.x & 7;
    int shift = s + 1;
    const int2* hs = hKV + (size_t)s * HSIZE;
    int4 cd = ((const int4*)coords)[p];
    int vx = cd.x >> shift, vy = cd.y >> shift, vz = cd.z >> shift;
    float inv = 1.0f / (float)(1 << shift);
    float fx = (float)(cd.x - (vx << shift)) * inv;  // exact dyadic
    float fy = (float)(cd.y - (vy << shift)) * inv;
    float fz = (float)(cd.z - (vz << shift)) * inv;
    int bx = (corner >> 2) & 1, by = (corner >> 1) & 1, bz = corner & 1;
    float wx = bx ? fx : 1.0f - fx;
    float wy = by ? fy : 1.0f - fy;
    float wz = bz ? fz : 1.0f - fz;
    float w = (wx * wy) * wz;  // same assoc order as jnp.prod
    int key = (((cd.w * 512 + (vx + bx)) * 512 + (vy + by)) * 512 + (vz + bz));
    unsigned h = ((unsigned)key * 2654435761u) >> 12;
    int g = -1;
    while (true) {
        int2 kv = hs[h];                // key + gid in ONE 8B load
        if (kv.x == key) { g = kv.y; break; }
        if (kv.x == -1) break;
        h = (h + 1) & HMASK;
    }
    if (g < 0) w = 0.0f;
    // first-occurrence argmax: strict greater, tie -> smaller corner. xor 1/2/4 stays in group.
    int j = corner;
    for (int m = 1; m < 8; m <<= 1) {
        float ow = __shfl_xor(w, m);
        int oj = __shfl_xor(j, m);
        int og = __shfl_xor(g, m);
        if (ow > w || (ow == w && oj < j)) { w = ow; j = oj; g = og; }
    }
    if (corner == 0) idx[(size_t)s * NPTS + p] = g;
}

// ---- fused: gather vmean + 3x (res@W1 -> relu*feats -> @W2 -> relu) + attention ----
__global__ __launch_bounds__(256) void fused_mlp(const float* __restrict__ feats,
                                                 const unsigned short* __restrict__ vmean,
                                                 const int* __restrict__ idx,
                                                 const unsigned short* __restrict__ W1T,
                                                 const unsigned short* __restrict__ W2T,
                                                 const float* __restrict__ b1,
                                                 const float* __restrict__ b2,
                                                 const float* __restrict__ Wa,
                                                 const float* __restrict__ ba,
                                                 float* __restrict__ out) {
    __shared__ __align__(16) unsigned short sH[4][16 * FP];

    int tid = threadIdx.x;
    int wave = tid >> 6, lane = tid & 63;
    int ln = lane & 15, quad = lane >> 4, ko = quad * 8;
    int b0 = blockIdx.x * 64;
    int mrow = wave * 16 + ln;
    int nA = b0 + mrow;
    bool vA = nA < NPTS;

    // A-fragment feats rows (f32), reused across scales
    float fA0[8], fA1[8];
    {
        const float* fr = feats + (size_t)(vA ? nA : 0) * 64;
#pragma unroll
        for (int j = 0; j < 8; ++j) { fA0[j] = fr[ko + j]; fA1[j] = fr[32 + ko + j]; }
    }
    // C-layout feats multipliers (row=wave*16+quad*4+r, col=nt*16+ln)
    float fC[4][4];
#pragma unroll
    for (int r = 0; r < 4; ++r) {
        int n = b0 + wave * 16 + quad * 4 + r;
        const float* fp = feats + (size_t)(n < NPTS ? n : 0) * 64;
#pragma unroll
        for (int nt = 0; nt < 4; ++nt) fC[nt][r] = (n < NPTS) ? fp[nt * 16 + ln] : 0.0f;
    }

    float4v ms[3][4];
    unsigned short* sHw = &sH[wave][0];

    for (int s = 0; s < 3; ++s) {
        // residual A-fragments: res = feats - vmean[gid]  (vmean row = 16B contiguous/lane)
        int g = vA ? idx[(size_t)s * NPTS + nA] : 0;
        const unsigned short* vr = vmean + ((size_t)s * NPTS + g) * 64;
        short8 u0 = *(const short8*)&vr[ko];
        short8 u1 = *(const short8*)&vr[32 + ko];
        short8 a0, a1;
#pragma unroll
        for (int j = 0; j < 8; ++j) {
            float r0 = vA ? fA0[j] - b2f((unsigned short)u0[j]) : 0.0f;
            float r1 = vA ? fA1[j] - b2f((unsigned short)u1[j]) : 0.0f;
            a0[j] = (short)f2b(r0);
            a1[j] = (short)f2b(r1);
        }

        // GEMM1: H = relu(res @ W1 + b1) * feats   (weights direct from global, L1-hot)
#pragma unroll
        for (int nt = 0; nt < 4; ++nt) {
            int ncol = nt * 16 + ln;
            const unsigned short* w1r = W1T + s * 4096 + ncol * 64;
            short8 bb0 = *(const short8*)&w1r[ko];
            short8 bb1 = *(const short8*)&w1r[32 + ko];
            float4v c = {0.f, 0.f, 0.f, 0.f};
            c = __builtin_amdgcn_mfma_f32_16x16x32_bf16(a0, bb0, c, 0, 0, 0);
            c = __builtin_amdgcn_mfma_f32_16x16x32_bf16(a1, bb1, c, 0, 0, 0);
            float bias = b1[s * 64 + ncol];
#pragma unroll
            for (int r = 0; r < 4; ++r) {
                float hv = fmaxf(c[r] + bias, 0.0f) * fC[nt][r];
                sHw[(quad * 4 + r) * FP + ncol] = f2b(hv);
            }
        }
        __threadfence_block();  // order wave-private LDS write -> read (no cross-wave dep)

        // GEMM2: ms = relu(H @ W2 + b2)
        short8 h0 = *(const short8*)&sHw[ln * FP + ko];
        short8 h1 = *(const short8*)&sHw[ln * FP + 32 + ko];
#pragma unroll
        for (int nt = 0; nt < 4; ++nt) {
            int ncol = nt * 16 + ln;
            const unsigned short* w2r = W2T + s * 4096 + ncol * 64;
            short8 bb0 = *(const short8*)&w2r[ko];
            short8 bb1 = *(const short8*)&w2r[32 + ko];
            float4v c = {0.f, 0.f, 0.f, 0.f};
            c = __builtin_amdgcn_mfma_f32_16x16x32_bf16(h0, bb0, c, 0, 0, 0);
            c = __builtin_amdgcn_mfma_f32_16x16x32_bf16(h1, bb1, c, 0, 0, 0);
            float bias2 = b2[s * 64 + ncol];
#pragma unroll
            for (int r = 0; r < 4; ++r) c[r] = fmaxf(c[r] + bias2, 0.0f);
            ms[s][nt] = c;
        }
    }

    // attention: att = sigmoid((ms0+ms1+ms2) @ Wa^T + ba); out = sum_s ms_s * att_s
    float4v sa[4];
#pragma unroll
    for (int nt = 0; nt < 4; ++nt) sa[nt] = ms[0][nt] + ms[1][nt] + ms[2][nt];
    float part[4][3];
#pragma unroll
    for (int r = 0; r < 4; ++r)
#pragma unroll
        for (int sh = 0; sh < 3; ++sh) {
            float p = 0.0f;
#pragma unroll
            for (int nt = 0; nt < 4; ++nt) p += sa[nt][r] * Wa[sh * 64 + nt * 16 + ln];
            part[r][sh] = p;
        }
    for (int m = 1; m < 16; m <<= 1)
#pragma unroll
        for (int r = 0; r < 4; ++r)
#pragma unroll
            for (int sh = 0; sh < 3; ++sh) part[r][sh] += __shfl_xor(part[r][sh], m);
    float att[4][3];
#pragma unroll
    for (int r = 0; r < 4; ++r)
#pragma unroll
        for (int sh = 0; sh < 3; ++sh)
            att[r][sh] = 1.0f / (1.0f + expf(-(part[r][sh] + ba[sh])));

#pragma unroll
    for (int nt = 0; nt < 4; ++nt)
#pragma unroll
        for (int r = 0; r < 4; ++r) {
            int n = b0 + wave * 16 + quad * 4 + r;
            if (n < NPTS) {
                float o = ms[0][nt][r] * att[r][0] + ms[1][nt][r] * att[r][1] +
                          ms[2][nt][r] * att[r][2];
                out[(size_t)n * 64 + nt * 16 + ln] = o;
            }
        }
}

extern "C" void kernel_launch(void* const* d_in, const int* in_sizes, int n_in,
                              void* d_out, int out_size, void* d_ws, size_t ws_size,
                              hipStream_t stream) {
    const float* feats = (const float*)d_in[0];
    const int* coords = (const int*)d_in[1];
    const float* W1 = (const float*)d_in[2];
    const float* b1 = (const float*)d_in[3];
    const float* W2 = (const float*)d_in[4];
    const float* b2 = (const float*)d_in[5];
    const float* Wa = (const float*)d_in[6];
    const float* ba = (const float*)d_in[7];
    float* out = (float*)d_out;

    char* ws = (char*)d_ws;
    size_t o = 0;
    unsigned short* W1T = (unsigned short*)(ws + o); o += 3 * 4096 * 2;
    unsigned short* W2T = (unsigned short*)(ws + o); o += 3 * 4096 * 2;
    o = (o + 255) & ~(size_t)255;
    unsigned short* vmean = (unsigned short*)(ws + o); o += (size_t)3 * NPTS * 64 * 2;
    int* idx = (int*)(ws + o); o += (size_t)3 * NPTS * 4;
    int* next = (int*)(ws + o); o += (size_t)3 * NPTS * 4;
    int* cslot = (int*)(ws + o); o += (size_t)3 * NPTS * 4;
    int* chead = (int*)(ws + o); o += (size_t)3 * NPTS * 4;
    o = (o + 255) & ~(size_t)255;
    unsigned long long* hKV = (unsigned long long*)(ws + o); o += (size_t)3 * HSIZE * 8;
    int* head = (int*)(ws + o); o += (size_t)3 * HSIZE * 4;  // contiguous with hKV
    int* gctr = (int*)(ws + o); o += 192 * 4;
    // total ~253 MB

    wconv<<<48, 256, 0, stream>>>(W1, W2, W1T, W2T, gctr);
    hipMemsetAsync(hKV, 0xFF, (size_t)3 * HSIZE * 12, stream);  // hKV + head in one memset

    const int BPS = (NPTS + 255) / 256;
    insert3<<<3 * BPS, 256, 0, stream>>>(coords, hKV, head, next, cslot, gctr);
    headfix3<<<(3 * NPTS + 255) / 256, 256, 0, stream>>>(cslot, head, gctr, chead);
    reduce3<<<(3 * NPTS * 16 + 255) / 256, 256, 0, stream>>>((const float4*)feats, chead,
                                                             next, gctr, (ushort4*)vmean);
    argmax3<<<3 * (NPTS / 32), 256, 0, stream>>>(coords, (const int2*)hKV, idx);
    fused_mlp<<<(NPTS + 63) / 64, 256, 0, stream>>>(feats, vmean, idx, W1T, W2T, b1, b2,
                                                    Wa, ba, out);
}

// Round 3
// 966.099 us; speedup vs baseline: 1.0081x; 1.0081x over previous
//
#include <hip/hip_runtime.h>
#include <hip/hip_bf16.h>
#include <stdint.h>

#define NPTS 500000
#define HSIZE (1u << 20)
#define HMASK (HSIZE - 1)
#define FP 72  // sH row pitch in ushorts: 144B rows -> 16B-aligned b128 reads, 2-way-free banks

typedef __attribute__((ext_vector_type(8))) short short8;
typedef __attribute__((ext_vector_type(4))) float float4v;

__device__ __forceinline__ unsigned short f2b(float f) {
    __hip_bfloat16 h = __float2bfloat16(f);
    return __builtin_bit_cast(unsigned short, h);
}
__device__ __forceinline__ float b2f(unsigned short u) {
    return __builtin_bit_cast(float, ((unsigned)u) << 16);
}

// ---- convert W1, W2 (f32, [s][c][j]) to bf16 transposed [s][j][c]; zero gctr ----
__global__ __launch_bounds__(256) void wconv(const float* __restrict__ W1,
                                             const float* __restrict__ W2,
                                             unsigned short* __restrict__ W1T,
                                             unsigned short* __restrict__ W2T,
                                             int* __restrict__ gctr) {
    int i = blockIdx.x * 256 + threadIdx.x;
    if (i < 192) gctr[i] = 0;
    if (i >= 3 * 4096) return;
    int s = i >> 12, rem = i & 4095, c = rem >> 6, j = rem & 63;
    W1T[s * 4096 + j * 64 + c] = f2b(W1[i]);
    W2T[s * 4096 + j * 64 + c] = f2b(W2[i]);
}

// ---- all 3 scales: 64-bit (key,gid) hash insert + per-slot chain + compact slot list ----
__global__ __launch_bounds__(256) void insert3(const int* __restrict__ coords,
                                               unsigned long long* __restrict__ hKV,
                                               int* __restrict__ head,
                                               int* __restrict__ next,
                                               int* __restrict__ cslot,
                                               int* __restrict__ gctr) {
    const int BPS = (NPTS + 255) / 256;  // 1954
    int s = blockIdx.x / BPS;
    int i = (blockIdx.x % BPS) * 256 + threadIdx.x;
    int shift = s + 1;
    unsigned long long* hs = hKV + (size_t)s * HSIZE;
    int* heads = head + (size_t)s * HSIZE;
    int* nexts = next + (size_t)s * NPTS;
    bool active = i < NPTS;
    unsigned h = 0;
    bool inserted = false;
    if (active) {
        int4 cd = ((const int4*)coords)[i];
        int key = (((cd.w * 512 + (cd.x >> shift)) * 512 + (cd.y >> shift)) * 512 +
                   (cd.z >> shift));
        unsigned long long want = (unsigned long long)(unsigned)key | 0xFFFFFFFF00000000ull;
        h = ((unsigned)key * 2654435761u) >> 12;  // top 20 bits
        while (true) {
            unsigned long long prev = atomicCAS(&hs[h], ~0ull, want);
            if (prev == ~0ull) { inserted = true; break; }
            if ((int)(prev & 0xFFFFFFFFull) == key) break;
            h = (h + 1) & HMASK;
        }
        nexts[i] = atomicExch(&heads[h], i);
    }
    unsigned long long mask = __ballot(inserted);
    if (mask) {
        int lane = threadIdx.x & 63;
        int leader = __ffsll((unsigned long long)mask) - 1;
        int base = 0;
        if (lane == leader) base = atomicAdd(&gctr[s * 64], __popcll(mask));
        base = __shfl(base, leader);
        if (inserted) {
            int gid = base + __popcll(mask & ((1ull << lane) - 1ull));
            ((int*)&hs[h])[1] = gid;  // high word; slot can never be CAS'd again
            cslot[(size_t)s * NPTS + gid] = (int)h;
        }
    }
}

// ---- resolve chain heads into a dense gid-indexed array (removes 2 dependent
// random loads from reduce3's critical path; 1.5M independent threads hide latency)
__global__ __launch_bounds__(256) void headfix3(const int* __restrict__ cslot,
                                                const int* __restrict__ head,
                                                const int* __restrict__ gctr,
                                                int* __restrict__ chead) {
    int t = blockIdx.x * 256 + threadIdx.x;
    int s = t / NPTS;
    if (s >= 3) return;
    int gid = t - s * NPTS;
    if (gid >= gctr[s * 64]) return;
    chead[(size_t)s * NPTS + gid] =
        head[(size_t)s * HSIZE + cslot[(size_t)s * NPTS + gid]];
}

// ---- all 3 scales: 16 lanes per group (4 chains in flight per wave), float4/lane,
// walk chain, exact mean -> bf16 vmean[gid] ----
__global__ __launch_bounds__(256) void reduce3(const float4* __restrict__ feats4,
                                               const int* __restrict__ chead,
                                               const int* __restrict__ next,
                                               const int* __restrict__ gctr,
                                               ushort4* __restrict__ vmean4) {
    int t = blockIdx.x * 256 + threadIdx.x;
    int sub = t >> 4;   // group index over 3*NPTS
    int sl = t & 15;    // sublane: 16 x float4 = 64 channels
    int s = sub / NPTS;
    if (s >= 3) return;
    int gid = sub - s * NPTS;
    if (gid >= gctr[s * 64]) return;
    int i = chead[(size_t)s * NPTS + gid];  // dense coalesced load
    const int* nexts = next + (size_t)s * NPTS;
    float4 sum = {0.f, 0.f, 0.f, 0.f};
    int cnt = 0;
    while (i >= 0) {
        float4 v = feats4[(size_t)i * 16 + sl];  // 256B coalesced row
        int ni = nexts[i];                       // independent of v
        sum.x += v.x; sum.y += v.y; sum.z += v.z; sum.w += v.w;
        cnt++;
        i = ni;
    }
    float cf = (float)cnt;
    ushort4 o;
    o.x = f2b(sum.x / cf);
    o.y = f2b(sum.y / cf);
    o.z = f2b(sum.z / cf);
    o.w = f2b(sum.w / cf);
    vmean4[((size_t)s * NPTS + gid) * 16 + sl] = o;
}

// ---- all 3 scales: 8 corners (8 pts/wave), exact first-max argmax, write winning gid ----
__global__ __launch_bounds__(256) void argmax3(const int* __restrict__ coords,
                                               const int2* __restrict__ hKV,
                                               int* __restrict__ idx) {
    const int PPB = 32;                 // points per block (256 thr / 8 corners)
    const int BPS = NPTS / PPB;         // 15625 exactly
    int s = blockIdx.x / BPS;
    int p = (blockIdx.x % BPS) * PPB + (threadIdx.x >> 3);
    int corner = threadIdx.x & 7;
    int shift = s + 1;
    const int2* hs = hKV + (size_t)s * HSIZE;
    int4 cd = ((const int4*)coords)[p];
    int vx = cd.x >> shift, vy = cd.y >> shift, vz = cd.z >> shift;
    float inv = 1.0f / (float)(1 << shift);
    float fx = (float)(cd.x - (vx << shift)) * inv;  // exact dyadic
    float fy = (float)(cd.y - (vy << shift)) * inv;
    float fz = (float)(cd.z - (vz << shift)) * inv;
    int bx = (corner >> 2) & 1, by = (corner >> 1) & 1, bz = corner & 1;
    float wx = bx ? fx : 1.0f - fx;
    float wy = by ? fy : 1.0f - fy;
    float wz = bz ? fz : 1.0f - fz;
    float w = (wx * wy) * wz;  // same assoc order as jnp.prod
    int key = (((cd.w * 512 + (vx + bx)) * 512 + (vy + by)) * 512 + (vz + bz));
    unsigned h = ((unsigned)key * 2654435761u) >> 12;
    int g = -1;
    while (true) {
        int2 kv = hs[h];                // key + gid in ONE 8B load
        if (kv.x == key) { g = kv.y; break; }
        if (kv.x == -1) break;
        h = (h + 1) & HMASK;
    }
    if (g < 0) w = 0.0f;
    // first-occurrence argmax: strict greater, tie -> smaller corner. xor 1/2/4 stays in group.
    int j = corner;
    for (int m = 1; m < 8; m <<= 1) {
        float ow = __shfl_xor(w, m);
        int oj = __shfl_xor(j, m);
        int og = __shfl_xor(g, m);
        if (ow > w || (ow == w && oj < j)) { w = ow; j = oj; g = og; }
    }
    if (corner == 0) idx[(size_t)s * NPTS + p] = g;
}

// ---- fused: gather vmean + 3x (res@W1 -> relu*feats -> @W2 -> relu) + attention ----
__global__ __launch_bounds__(256) void fused_mlp(const float* __restrict__ feats,
                                                 const unsigned short* __restrict__ vmean,
                                                 const int* __restrict__ idx,
                                                 const unsigned short* __restrict__ W1T,
                                                 const unsigned short* __restrict__ W2T,
                                                 const float* __restrict__ b1,
                                                 const float* __restrict__ b2,
                                                 const float* __restrict__ Wa,
                                                 const float* __restrict__ ba,
                                                 float* __restrict__ out) {
    __shared__ __align__(16) unsigned short sH[4][16 * FP];

    int tid = threadIdx.x;
    int wave = tid >> 6, lane = tid & 63;
    int ln = lane & 15, quad = lane >> 4, ko = quad * 8;
    int b0 = blockIdx.x * 64;
    int mrow = wave * 16 + ln;
    int nA = b0 + mrow;
    bool vA = nA < NPTS;

    // ---- prefetch: issue ALL 3 idx loads first (longest dependent chain),
    // then the independent feats loads (fill idx-latency window), then all 6
    // vmean gathers. Converts 3 serial {idx->gather} chains into one. ----
    int gg[3];
#pragma unroll
    for (int s = 0; s < 3; ++s) gg[s] = vA ? idx[(size_t)s * NPTS + nA] : 0;

    // A-fragment feats rows (f32), reused across scales
    float fA0[8], fA1[8];
    {
        const float* fr = feats + (size_t)(vA ? nA : 0) * 64;
#pragma unroll
        for (int j = 0; j < 8; ++j) { fA0[j] = fr[ko + j]; fA1[j] = fr[32 + ko + j]; }
    }
    // C-layout feats multipliers (row=wave*16+quad*4+r, col=nt*16+ln)
    float fC[4][4];
#pragma unroll
    for (int r = 0; r < 4; ++r) {
        int n = b0 + wave * 16 + quad * 4 + r;
        const float* fp = feats + (size_t)(n < NPTS ? n : 0) * 64;
#pragma unroll
        for (int nt = 0; nt < 4; ++nt) fC[nt][r] = (n < NPTS) ? fp[nt * 16 + ln] : 0.0f;
    }

    // 6 independent vmean gathers in flight (16B each, 2 per scale)
    short8 u0v[3], u1v[3];
#pragma unroll
    for (int s = 0; s < 3; ++s) {
        const unsigned short* vr = vmean + ((size_t)s * NPTS + gg[s]) * 64;
        u0v[s] = *(const short8*)&vr[ko];
        u1v[s] = *(const short8*)&vr[32 + ko];
    }

    float4v ms[3][4];
    unsigned short* sHw = &sH[wave][0];

#pragma unroll
    for (int s = 0; s < 3; ++s) {
        // residual A-fragments: res = feats - vmean[gid]
        short8 u0 = u0v[s], u1 = u1v[s];
        short8 a0, a1;
#pragma unroll
        for (int j = 0; j < 8; ++j) {
            float r0 = vA ? fA0[j] - b2f((unsigned short)u0[j]) : 0.0f;
            float r1 = vA ? fA1[j] - b2f((unsigned short)u1[j]) : 0.0f;
            a0[j] = (short)f2b(r0);
            a1[j] = (short)f2b(r1);
        }

        // GEMM1: H = relu(res @ W1 + b1) * feats   (weights direct from global, L1-hot)
#pragma unroll
        for (int nt = 0; nt < 4; ++nt) {
            int ncol = nt * 16 + ln;
            const unsigned short* w1r = W1T + s * 4096 + ncol * 64;
            short8 bb0 = *(const short8*)&w1r[ko];
            short8 bb1 = *(const short8*)&w1r[32 + ko];
            float4v c = {0.f, 0.f, 0.f, 0.f};
            c = __builtin_amdgcn_mfma_f32_16x16x32_bf16(a0, bb0, c, 0, 0, 0);
            c = __builtin_amdgcn_mfma_f32_16x16x32_bf16(a1, bb1, c, 0, 0, 0);
            float bias = b1[s * 64 + ncol];
#pragma unroll
            for (int r = 0; r < 4; ++r) {
                float hv = fmaxf(c[r] + bias, 0.0f) * fC[nt][r];
                sHw[(quad * 4 + r) * FP + ncol] = f2b(hv);
            }
        }
        __threadfence_block();  // order wave-private LDS write -> read (no cross-wave dep)

        // GEMM2: ms = relu(H @ W2 + b2)
        short8 h0 = *(const short8*)&sHw[ln * FP + ko];
        short8 h1 = *(const short8*)&sHw[ln * FP + 32 + ko];
#pragma unroll
        for (int nt = 0; nt < 4; ++nt) {
            int ncol = nt * 16 + ln;
            const unsigned short* w2r = W2T + s * 4096 + ncol * 64;
            short8 bb0 = *(const short8*)&w2r[ko];
            short8 bb1 = *(const short8*)&w2r[32 + ko];
            float4v c = {0.f, 0.f, 0.f, 0.f};
            c = __builtin_amdgcn_mfma_f32_16x16x32_bf16(h0, bb0, c, 0, 0, 0);
            c = __builtin_amdgcn_mfma_f32_16x16x32_bf16(h1, bb1, c, 0, 0, 0);
            float bias2 = b2[s * 64 + ncol];
#pragma unroll
            for (int r = 0; r < 4; ++r) c[r] = fmaxf(c[r] + bias2, 0.0f);
            ms[s][nt] = c;
        }
    }

    // attention: att = sigmoid((ms0+ms1+ms2) @ Wa^T + ba); out = sum_s ms_s * att_s
    float4v sa[4];
#pragma unroll
    for (int nt = 0; nt < 4; ++nt) sa[nt] = ms[0][nt] + ms[1][nt] + ms[2][nt];
    float part[4][3];
#pragma unroll
    for (int r = 0; r < 4; ++r)
#pragma unroll
        for (int sh = 0; sh < 3; ++sh) {
            float p = 0.0f;
#pragma unroll
            for (int nt = 0; nt < 4; ++nt) p += sa[nt][r] * Wa[sh * 64 + nt * 16 + ln];
            part[r][sh] = p;
        }
    for (int m = 1; m < 16; m <<= 1)
#pragma unroll
        for (int r = 0; r < 4; ++r)
#pragma unroll
            for (int sh = 0; sh < 3; ++sh) part[r][sh] += __shfl_xor(part[r][sh], m);
    float att[4][3];
#pragma unroll
    for (int r = 0; r < 4; ++r)
#pragma unroll
        for (int sh = 0; sh < 3; ++sh)
            att[r][sh] = 1.0f / (1.0f + expf(-(part[r][sh] + ba[sh])));

#pragma unroll
    for (int nt = 0; nt < 4; ++nt)
#pragma unroll
        for (int r = 0; r < 4; ++r) {
            int n = b0 + wave * 16 + quad * 4 + r;
            if (n < NPTS) {
                float o = ms[0][nt][r] * att[r][0] + ms[1][nt][r] * att[r][1] +
                          ms[2][nt][r] * att[r][2];
                out[(size_t)n * 64 + nt * 16 + ln] = o;
            }
        }
}

extern "C" void kernel_launch(void* const* d_in, const int* in_sizes, int n_in,
                              void* d_out, int out_size, void* d_ws, size_t ws_size,
                              hipStream_t stream) {
    const float* feats = (const float*)d_in[0];
    const int* coords = (const int*)d_in[1];
    const float* W1 = (const float*)d_in[2];
    const float* b1 = (const float*)d_in[3];
    const float* W2 = (const float*)d_in[4];
    const float* b2 = (const float*)d_in[5];
    const float* Wa = (const float*)d_in[6];
    const float* ba = (const float*)d_in[7];
    float* out = (float*)d_out;

    char* ws = (char*)d_ws;
    size_t o = 0;
    unsigned short* W1T = (unsigned short*)(ws + o); o += 3 * 4096 * 2;
    unsigned short* W2T = (unsigned short*)(ws + o); o += 3 * 4096 * 2;
    o = (o + 255) & ~(size_t)255;
    unsigned short* vmean = (unsigned short*)(ws + o); o += (size_t)3 * NPTS * 64 * 2;
    int* idx = (int*)(ws + o); o += (size_t)3 * NPTS * 4;
    int* next = (int*)(ws + o); o += (size_t)3 * NPTS * 4;
    int* cslot = (int*)(ws + o); o += (size_t)3 * NPTS * 4;
    int* chead = (int*)(ws + o); o += (size_t)3 * NPTS * 4;
    o = (o + 255) & ~(size_t)255;
    unsigned long long* hKV = (unsigned long long*)(ws + o); o += (size_t)3 * HSIZE * 8;
    int* head = (int*)(ws + o); o += (size_t)3 * HSIZE * 4;  // contiguous with hKV
    int* gctr = (int*)(ws + o); o += 192 * 4;
    // total ~253 MB

    wconv<<<48, 256, 0, stream>>>(W1, W2, W1T, W2T, gctr);
    hipMemsetAsync(hKV, 0xFF, (size_t)3 * HSIZE * 12, stream);  // hKV + head in one memset

    const int BPS = (NPTS + 255) / 256;
    insert3<<<3 * BPS, 256, 0, stream>>>(coords, hKV, head, next, cslot, gctr);
    headfix3<<<(3 * NPTS + 255) / 256, 256, 0, stream>>>(cslot, head, gctr, chead);
    reduce3<<<(3 * NPTS * 16 + 255) / 256, 256, 0, stream>>>((const float4*)feats, chead,
                                                             next, gctr, (ushort4*)vmean);
    argmax3<<<3 * (NPTS / 32), 256, 0, stream>>>(coords, (const int2*)hKV, idx);
    fused_mlp<<<(NPTS + 63) / 64, 256, 0, stream>>>(feats, vmean, idx, W1T, W2T, b1, b2,
                                                    Wa, ba, out);
}